// Round 6
// baseline (515.007 us; speedup 1.0000x reference)
//
#include <hip/hip_runtime.h>
#include <hip/hip_bf16.h>

typedef unsigned int uint;
typedef unsigned short ushort_t;
typedef unsigned long long u64;
typedef __attribute__((ext_vector_type(8))) short short8;
typedef __attribute__((ext_vector_type(4))) float floatx4;

#define NB 8
#define NP 4096
#define ND 128
#define NK 16
#define NC 64
#define NPTS 32768   // NB*NP
#define CAP 1280     // candidate buffer (R3-proven sufficient for the fallback threshold)

__device__ __forceinline__ float bf2f(ushort_t h){ return __uint_as_float(((uint)h)<<16); }
__device__ __forceinline__ ushort_t f2bf(float f){
  uint u = __float_as_uint(f);
  u = u + 0x7FFFu + ((u>>16)&1u);
  return (ushort_t)(u>>16);
}
// dtype-polymorphic input load (f32=1: fp32 array, f32=0: bf16 array)
__device__ __forceinline__ float ldin(const void* p, long i, int f32){
  return f32 ? ((const float*)p)[i] : bf2f(((const ushort_t*)p)[i]);
}
// dtype-polymorphic output store
__device__ __forceinline__ void stout(void* o, long i, float v, int f32){
  if (f32) ((float*)o)[i] = v; else ((ushort_t*)o)[i] = f2bf(v);
}

// ---------------- kernel D: detect input dtype ----------------
__global__ __launch_bounds__(256) void k_detect(const uint* __restrict__ w, int* __restrict__ flag){
  __shared__ int cnt;
  if (threadIdx.x == 0) cnt = 0;
  __syncthreads();
  int c = 0;
  for (int i = threadIdx.x; i < 512; i += 256){
    uint u = w[i];
    uint e = (u >> 7) & 0xFFu;
    c += (e >= 100u && e < 128u) ? 1 : 0;
  }
  atomicAdd(&cnt, c);
  __syncthreads();
  if (threadIdx.x == 0) *flag = (cnt < 256) ? 1 : 0;   // 1 => fp32 inputs/outputs
}

// ---------------- kernel 0: pos -> float4 {x,y,z,sq} ----------------
__global__ __launch_bounds__(256) void k_posf(const void* __restrict__ pos, float4* __restrict__ posf,
                                              const int* __restrict__ flag){
#pragma clang fp contract(off)
  int f32 = *flag;
  int p = blockIdx.x*256 + threadIdx.x;
  if (p >= NPTS) return;
  float x = ldin(pos, (long)p*3+0, f32);
  float y = ldin(pos, (long)p*3+1, f32);
  float z = ldin(pos, (long)p*3+2, f32);
  float px = x*x; float py = y*y; float pz = z*z;
  float sq = (px + py) + pz;   // match np.sum(pos*pos,-1) sequential order
  posf[p] = make_float4(x, y, z, sq);
}

// ---------------- kernel 1: exact 17-NN selection (one block per query) ----------------
// Threshold ut from a two-level bit-histogram (fast path). KEY SAFETY PROPERTY:
// for ANY ut, {u < ut} is downward-closed, so if 17 <= cnt <= CAP the collected
// set provably contains the true top-17 and exact ranking is correct. If the
// count check fails, re-collect with the R3-proven per-wave binary-search
// threshold. Correctness does not depend on the histogram logic.
__global__ __launch_bounds__(256) void k_knn(const float4* __restrict__ posf, int* __restrict__ knn){
#pragma clang fp contract(off)
  __shared__ u64 scand[CAP];
  __shared__ __align__(16) int hist[256];
  __shared__ int scnt, sb1, scum1, sbin;
  __shared__ uint suT;
  int qid = blockIdx.x;
  int b = qid >> 12;
  int tid = threadIdx.x;
  int lane = tid & 63;
  if (tid == 0){ scnt = 0; sbin = 255; }
  hist[tid] = 0;
  __syncthreads();
  const float4 q = posf[qid];
  int jbase = b << 12;
  float d2[16]; uint ub[16];
  #pragma unroll
  for (int s = 0; s < 16; ++s){
    int j = s*256 + tid;
    float4 pj = posf[jbase + j];
    float ax = q.x*pj.x; float ay = q.y*pj.y; float az = q.z*pj.z;
    float dot = (ax + ay) + az;                 // match np einsum order
    float t  = q.w + pj.w;                      // sq_i + sq_j (one rounding)
    float v  = t - 2.0f*dot;                    // 2*dot exact, one rounding
    d2[s] = v;
    ub[s] = __float_as_uint(fmaxf(v, 0.0f));    // nonneg float: uint order == float order
  }
  // ---- fast threshold: pass 1 histogram exponent byte ----
  #pragma unroll
  for (int s = 0; s < 16; ++s) atomicAdd(&hist[ub[s] >> 23], 1);
  __syncthreads();
  if (tid < 64){   // wave 0: 4 bins/lane, inclusive prefix scan, find crossing bin
    int4 h = *(const int4*)&hist[tid*4];
    int ssum = h.x + h.y + h.z + h.w;
    int inc = ssum;
    #pragma unroll
    for (int off = 1; off < 64; off <<= 1){ int t = __shfl_up(inc, off, 64); if (tid >= off) inc += t; }
    u64 bal = __ballot(inc >= 17);
    int cl = __ffsll(bal) - 1;
    if (tid == cl){
      int c = inc - ssum;
      int bsel = tid*4;
      if (c + h.x < 17){ c += h.x; bsel++;
        if (c + h.y < 17){ c += h.y; bsel++;
          if (c + h.z < 17){ c += h.z; bsel++; } } }
      sb1 = bsel; scum1 = c;
    }
  }
  __syncthreads();
  int b1 = sb1, cum1 = scum1;
  hist[tid] = 0;
  __syncthreads();
  // pass 2: histogram next 8 mantissa bits within crossing bin
  #pragma unroll
  for (int s = 0; s < 16; ++s){
    if ((int)(ub[s] >> 23) == b1) atomicAdd(&hist[(ub[s] >> 15) & 0xFF], 1);
  }
  __syncthreads();
  if (tid < 64){
    int4 h = *(const int4*)&hist[tid*4];
    int ssum = h.x + h.y + h.z + h.w;
    int inc = ssum;
    #pragma unroll
    for (int off = 1; off < 64; off <<= 1){ int t = __shfl_up(inc, off, 64); if (tid >= off) inc += t; }
    u64 bal = __ballot(cum1 + inc >= 17);
    int cl = __ffsll(bal) - 1;
    if (tid == cl){
      int c = cum1 + inc - ssum;
      int bsel = tid*4;
      if (c + h.x < 17){ c += h.x; bsel++;
        if (c + h.y < 17){ c += h.y; bsel++;
          if (c + h.z < 17){ c += h.z; bsel++; } } }
      suT = ((uint)b1 << 23) | ((uint)(bsel + 1) << 15);
    }
  }
  __syncthreads();
  uint ut = suT;
  // ---- collection (fast-path threshold) ----
  #pragma unroll
  for (int s = 0; s < 16; ++s){
    if (ub[s] < ut){
      int p = atomicAdd(&scnt, 1);
      if (p < CAP){
        uint w = __float_as_uint(d2[s]);
        uint sd = w ^ ((w & 0x80000000u) ? 0xFFFFFFFFu : 0x80000000u); // signed monotone map
        scand[p] = (((u64)sd) << 32) | (uint)(s*256 + tid);
      }
    }
  }
  __syncthreads();
  int cnt = scnt;
  // ---- safety net: if the fast threshold failed, redo with R3-proven search ----
  if (cnt < 17 || cnt > CAP){       // block-uniform condition (shared scnt)
    __syncthreads();                // all reads of scnt done before reset
    if (tid == 0) scnt = 0;
    __syncthreads();
    // R3-proven per-wave binary search on exponent bins (uint compare == float compare)
    int lo = 0, hi = 255;
    while (lo < hi){
      int mid = (lo + hi) >> 1;
      uint T = (uint)(mid+1) << 23;
      int c = 0;
      #pragma unroll
      for (int s = 0; s < 16; ++s) c += (ub[s] < T) ? 1 : 0;
      #pragma unroll
      for (int off = 1; off < 64; off <<= 1) c += __shfl_xor(c, off, 64);
      if (c >= 17) hi = mid; else lo = mid + 1;
    }
    if (lane == 0) atomicMin(&sbin, lo);
    __syncthreads();
    uint ut2 = (uint)(sbin+1) << 23;
    #pragma unroll
    for (int s = 0; s < 16; ++s){
      if (ub[s] < ut2){
        int p = atomicAdd(&scnt, 1);
        if (p < CAP){
          uint w = __float_as_uint(d2[s]);
          uint sd = w ^ ((w & 0x80000000u) ? 0xFFFFFFFFu : 0x80000000u);
          scand[p] = (((u64)sd) << 32) | (uint)(s*256 + tid);
        }
      }
    }
    __syncthreads();
    cnt = scnt;
  }
  if (cnt > CAP) cnt = CAP;
  // ---- exact rank among candidates (unique keys -> ranks 0..cnt-1 all present) ----
  for (int base = 0; base < cnt; base += 256){
    int ci = base + tid;
    u64 mykey = (ci < cnt) ? scand[ci] : ~0ull;
    int r = 0;
    for (int i = 0; i < cnt; ++i){
      r += (scand[i] < mykey) ? 1 : 0;
    }
    if (ci < cnt && r >= 1 && r <= 16){
      knn[qid*16 + (r-1)] = (int)(mykey & 0xFFFFFFFFu);  // local j in [0,4096)
    }
  }
}

// ---------------- kernel W: weight prep ----------------
__global__ __launch_bounds__(256) void k_wprep(const void* __restrict__ Wf, const void* __restrict__ bfv,
                        const void* __restrict__ Wm1, const void* __restrict__ bm1,
                        const void* __restrict__ Wm2, const void* __restrict__ bm2,
                        const void* __restrict__ Wl, const void* __restrict__ bl,
                        ushort_t* __restrict__ WcatT, float* __restrict__ biasT,
                        ushort_t* __restrict__ WTA1, ushort_t* __restrict__ WTB2, ushort_t* __restrict__ WTC3,
                        const int* __restrict__ flag){
  int f32 = *flag;
  int id = blockIdx.x*256 + threadIdx.x;
  if (id < 40960){
    int n = id >> 7, k = id & 127;
    float v;
    if (n < 64)       v = ldin(Wf, (long)k*64 + n, f32) - ldin(Wf, (long)(256+k)*64 + n, f32);
    else if (n < 128) v = ldin(Wf, (long)(128+k)*64 + (n-64), f32) + ldin(Wf, (long)(256+k)*64 + (n-64), f32);
    else if (n < 192) v = ldin(Wm1, (long)(64+k)*64 + (n-128), f32);
    else if (n < 256) v = ldin(Wm2, (long)(128+k)*64 + (n-192), f32);
    else              v = ldin(Wl, (long)(192+k)*64 + (n-256), f32);
    WcatT[id] = f2bf(v);
  } else if (id < 41280){
    int n = id - 40960;
    float bv;
    if (n < 64)       bv = ldin(bfv, n, f32);
    else if (n < 128) bv = 0.0f;
    else if (n < 192) bv = ldin(bm1, n-128, f32);
    else if (n < 256) bv = ldin(bm2, n-192, f32);
    else              bv = ldin(bl, n-256, f32);
    biasT[n] = bv;
  } else if (id < 45376){      // WTA1 64x64
    int t = id - 41280; int n = t >> 6, k = t & 63;
    WTA1[t] = f2bf(ldin(Wm1, (long)k*64 + n, f32));
  } else if (id < 53568){      // WTB2 64x128
    int t = id - 45376; int n = t >> 7, k = t & 127;
    WTB2[t] = f2bf(ldin(Wm2, (long)k*64 + n, f32));
  } else if (id < 65856){      // WTC3 64x192
    int t = id - 53568; int n = t / 192, k = t % 192;
    WTC3[t] = f2bf(ldin(Wl, (long)k*64 + n, f32));
  }
}

// ---------------- kernel 2: P = X @ Wcat + bias  (bf16 out, rows 32768 x 320) ----------------
__global__ __launch_bounds__(256) void k_pgemm(const void* __restrict__ xv, const ushort_t* __restrict__ WcatT,
                                               const float* __restrict__ biasT, ushort_t* __restrict__ P,
                                               const int* __restrict__ flag){
  int f32 = *flag;
  int wave = threadIdx.x >> 6, lane = threadIdx.x & 63;
  int rowbase = blockIdx.x*64 + wave*16;
  int quad = lane >> 4, col = lane & 15;
  floatx4 acc[20];
  #pragma unroll
  for (int i = 0; i < 20; ++i) acc[i] = (floatx4){0.f,0.f,0.f,0.f};
  #pragma unroll
  for (int kk = 0; kk < 4; ++kk){
    int k = kk*32 + quad*8;
    short8 a;
    if (f32){
      const float* xf = (const float*)xv + (long)(rowbase + col)*128 + k;
      #pragma unroll
      for (int i = 0; i < 8; ++i) a[i] = (short)f2bf(xf[i]);
    } else {
      a = *(const short8*)((const ushort_t*)xv + (long)(rowbase + col)*128 + k);
    }
    #pragma unroll
    for (int nt = 0; nt < 20; ++nt){
      short8 bb = *(const short8*)(WcatT + (nt*16 + col)*128 + k);
      acc[nt] = __builtin_amdgcn_mfma_f32_16x16x32_bf16(a, bb, acc[nt], 0, 0, 0);
    }
  }
  #pragma unroll
  for (int nt = 0; nt < 20; ++nt){
    float bv = biasT[nt*16 + col];
    #pragma unroll
    for (int r = 0; r < 4; ++r){
      int m = quad*4 + r;
      P[(long)(rowbase + m)*320 + nt*16 + col] = f2bf(acc[nt][r] + bv);
    }
  }
}

// ---------------- kernel 3: per-edge chain + max over K (one wave per query) ----------------
__global__ __launch_bounds__(256) void k_edge(const void* __restrict__ x, const ushort_t* __restrict__ P,
                                              const int* __restrict__ knn,
                                              const ushort_t* __restrict__ WTA1, const ushort_t* __restrict__ WTB2,
                                              const ushort_t* __restrict__ WTC3, void* __restrict__ out,
                                              const int* __restrict__ flag){
  __shared__ __align__(16) ushort_t hb[4][3][16*72];   // per-wave h1,h2,h3 tiles, 72-elem padded rows
  int f32 = *flag;
  int wave = threadIdx.x >> 6, lane = threadIdx.x & 63;
  int qid = blockIdx.x*4 + wave;
  int b = qid >> 12;
  int quad = lane >> 4, col = lane & 15;
  ushort_t* h1p = hb[wave][0];
  ushort_t* h2p = hb[wave][1];
  ushort_t* h3p = hb[wave][2];
  const ushort_t* Prow = P + (long)qid*320;

  float u1v[4], u2v[4], u3v[4];
  #pragma unroll
  for (int nt = 0; nt < 4; ++nt){
    u1v[nt] = bf2f(Prow[128 + nt*16 + col]);
    u2v[nt] = bf2f(Prow[192 + nt*16 + col]);
    u3v[nt] = bf2f(Prow[256 + nt*16 + col]);
  }

  // h1 = relu(q_i + k_j): lane -> edge e=lane>>2, col-group cg=lane&3
  {
    int e = lane >> 2, cg = lane & 3;
    int nbr = knn[qid*16 + e] & (NP - 1);   // mask: any corrupt idx stays in-bounds
    const ushort_t* Pk = P + ((long)(b<<12) + nbr)*320 + 64 + cg*16;
    const ushort_t* Pq = Prow + cg*16;
    short8 k0 = *(const short8*)(Pk);
    short8 k1 = *(const short8*)(Pk + 8);
    short8 q0 = *(const short8*)(Pq);
    short8 q1 = *(const short8*)(Pq + 8);
    short8 h0, h1r;
    #pragma unroll
    for (int i = 0; i < 8; ++i){
      float v = fmaxf(bf2f((ushort_t)q0[i]) + bf2f((ushort_t)k0[i]), 0.0f);
      h0[i] = (short)f2bf(v);
      float w = fmaxf(bf2f((ushort_t)q1[i]) + bf2f((ushort_t)k1[i]), 0.0f);
      h1r[i] = (short)f2bf(w);
    }
    *(short8*)(h1p + e*72 + cg*16)     = h0;
    *(short8*)(h1p + e*72 + cg*16 + 8) = h1r;
  }
  __syncthreads();

  // layer 2: h2 = relu(h1 @ A1 + u1)
  floatx4 acc2[4];
  #pragma unroll
  for (int nt = 0; nt < 4; ++nt) acc2[nt] = (floatx4){0.f,0.f,0.f,0.f};
  #pragma unroll
  for (int kk = 0; kk < 2; ++kk){
    int k = kk*32 + quad*8;
    short8 a = *(const short8*)(h1p + col*72 + k);
    #pragma unroll
    for (int nt = 0; nt < 4; ++nt){
      short8 bb = *(const short8*)(WTA1 + (nt*16 + col)*64 + k);
      acc2[nt] = __builtin_amdgcn_mfma_f32_16x16x32_bf16(a, bb, acc2[nt], 0, 0, 0);
    }
  }
  #pragma unroll
  for (int nt = 0; nt < 4; ++nt){
    #pragma unroll
    for (int r = 0; r < 4; ++r){
      int m = quad*4 + r;
      h2p[m*72 + nt*16 + col] = f2bf(fmaxf(acc2[nt][r] + u1v[nt], 0.0f));
    }
  }
  __syncthreads();

  // layer 3: h3 = relu([h2|h1] @ B2 + u2)
  floatx4 acc3[4];
  #pragma unroll
  for (int nt = 0; nt < 4; ++nt) acc3[nt] = (floatx4){0.f,0.f,0.f,0.f};
  #pragma unroll
  for (int kk = 0; kk < 4; ++kk){
    int kg = kk*32 + quad*8;
    const ushort_t* src = (kk < 2) ? h2p : h1p;
    int kl = (kk < 2) ? kg : (kg - 64);
    short8 a = *(const short8*)(src + col*72 + kl);
    #pragma unroll
    for (int nt = 0; nt < 4; ++nt){
      short8 bb = *(const short8*)(WTB2 + (nt*16 + col)*128 + kg);
      acc3[nt] = __builtin_amdgcn_mfma_f32_16x16x32_bf16(a, bb, acc3[nt], 0, 0, 0);
    }
  }
  #pragma unroll
  for (int nt = 0; nt < 4; ++nt){
    #pragma unroll
    for (int r = 0; r < 4; ++r){
      int m = quad*4 + r;
      h3p[m*72 + nt*16 + col] = f2bf(fmaxf(acc3[nt][r] + u2v[nt], 0.0f));
    }
  }
  __syncthreads();

  // layer 4: o = [h3|h2|h1] @ C3 + u3  (no relu)
  floatx4 acc4[4];
  #pragma unroll
  for (int nt = 0; nt < 4; ++nt) acc4[nt] = (floatx4){0.f,0.f,0.f,0.f};
  #pragma unroll
  for (int kk = 0; kk < 6; ++kk){
    int kg = kk*32 + quad*8;
    const ushort_t* src = (kk < 2) ? h3p : ((kk < 4) ? h2p : h1p);
    int kl = (kk < 2) ? kg : ((kk < 4) ? (kg - 64) : (kg - 128));
    short8 a = *(const short8*)(src + col*72 + kl);
    #pragma unroll
    for (int nt = 0; nt < 4; ++nt){
      short8 bb = *(const short8*)(WTC3 + (nt*16 + col)*192 + kg);
      acc4[nt] = __builtin_amdgcn_mfma_f32_16x16x32_bf16(a, bb, acc4[nt], 0, 0, 0);
    }
  }

  // output: [max o | max h3 | max h2 | max h1 | x]
  long outb = (long)qid*384;
  #pragma unroll
  for (int nt = 0; nt < 4; ++nt){
    float m0 = fmaxf(fmaxf(acc4[nt][0], acc4[nt][1]), fmaxf(acc4[nt][2], acc4[nt][3])) + u3v[nt];
    m0 = fmaxf(m0, __shfl_xor(m0, 16, 64));
    m0 = fmaxf(m0, __shfl_xor(m0, 32, 64));
    if (lane < 16) stout(out, outb + nt*16 + lane, m0, f32);
  }
  {
    ushort_t mx3 = 0, mx2 = 0, mx1 = 0;
    #pragma unroll
    for (int m = 0; m < 16; ++m){
      ushort_t v3 = h3p[m*72 + lane]; if (v3 > mx3) mx3 = v3;
      ushort_t v2 = h2p[m*72 + lane]; if (v2 > mx2) mx2 = v2;
      ushort_t v1 = h1p[m*72 + lane]; if (v1 > mx1) mx1 = v1;
    }
    // post-relu bf16 >= 0: bit compare == float compare; bf2f/f2bf round-trip is identity
    stout(out, outb + 64  + lane, bf2f(mx3), f32);
    stout(out, outb + 128 + lane, bf2f(mx2), f32);
    stout(out, outb + 192 + lane, bf2f(mx1), f32);
    stout(out, outb + 256 + lane,      ldin(x, (long)qid*128 + lane, f32), f32);
    stout(out, outb + 256 + 64 + lane, ldin(x, (long)qid*128 + 64 + lane, f32), f32);
  }
}

extern "C" void kernel_launch(void* const* d_in, const int* in_sizes, int n_in,
                              void* d_out, int out_size, void* d_ws, size_t ws_size,
                              hipStream_t stream){
  const void* x   = d_in[0];
  const void* pos = d_in[1];
  const void* Wf  = d_in[2];
  const void* bfv = d_in[3];
  const void* Wm1 = d_in[4];
  const void* bm1 = d_in[5];
  const void* Wm2 = d_in[6];
  const void* bm2 = d_in[7];
  const void* Wl  = d_in[8];
  const void* bl  = d_in[9];
  char* ws = (char*)d_ws;
  float4*   posf  = (float4*)(ws + 0);                 // 524288 B
  int*      knn   = (int*)(ws + 524288);               // 2097152 B
  ushort_t* P     = (ushort_t*)(ws + 2621440);         // 20971520 B
  ushort_t* WcatT = (ushort_t*)(ws + 23592960);        // 81920 B
  float*    biasT = (float*)(ws + 23674880);           // 1280 B
  ushort_t* WTA1  = (ushort_t*)(ws + 23676160);        // 8192 B
  ushort_t* WTB2  = (ushort_t*)(ws + 23684352);        // 16384 B
  ushort_t* WTC3  = (ushort_t*)(ws + 23700736);        // 24576 B
  int*      flag  = (int*)(ws + 23725312);             // 4 B (total ~22.63 MB)

  k_detect<<<1,     256, 0, stream>>>((const uint*)Wf, flag);
  k_posf <<<128,   256, 0, stream>>>(pos, posf, flag);
  k_wprep<<<258,   256, 0, stream>>>(Wf, bfv, Wm1, bm1, Wm2, bm2, Wl, bl, WcatT, biasT, WTA1, WTB2, WTC3, flag);
  k_knn  <<<32768, 256, 0, stream>>>(posf, knn);
  k_pgemm<<<512,   256, 0, stream>>>(x, WcatT, biasT, P, flag);
  k_edge <<<8192,  256, 0, stream>>>(x, P, knn, WTA1, WTB2, WTC3, d_out, flag);
}

// Round 7
// 502.170 us; speedup vs baseline: 1.0256x; 1.0256x over previous
//
#include <hip/hip_runtime.h>
#include <hip/hip_bf16.h>

typedef unsigned int uint;
typedef unsigned short ushort_t;
typedef unsigned long long u64;
typedef __attribute__((ext_vector_type(8))) short short8;
typedef __attribute__((ext_vector_type(4))) float floatx4;

#define NB 8
#define NP 4096
#define ND 128
#define NK 16
#define NC 64
#define NPTS 32768   // NB*NP
#define CAP 1280     // candidate buffer; 12-bit threshold keeps cnt ~17-64 typically

__device__ __forceinline__ float bf2f(ushort_t h){ return __uint_as_float(((uint)h)<<16); }
__device__ __forceinline__ ushort_t f2bf(float f){
  uint u = __float_as_uint(f);
  u = u + 0x7FFFu + ((u>>16)&1u);
  return (ushort_t)(u>>16);
}
// dtype-polymorphic input load (f32=1: fp32 array, f32=0: bf16 array)
__device__ __forceinline__ float ldin(const void* p, long i, int f32){
  return f32 ? ((const float*)p)[i] : bf2f(((const ushort_t*)p)[i]);
}
// dtype-polymorphic output store
__device__ __forceinline__ void stout(void* o, long i, float v, int f32){
  if (f32) ((float*)o)[i] = v; else ((ushort_t*)o)[i] = f2bf(v);
}

// ---------------- kernel D: detect input dtype ----------------
__global__ __launch_bounds__(256) void k_detect(const uint* __restrict__ w, int* __restrict__ flag){
  __shared__ int cnt;
  if (threadIdx.x == 0) cnt = 0;
  __syncthreads();
  int c = 0;
  for (int i = threadIdx.x; i < 512; i += 256){
    uint u = w[i];
    uint e = (u >> 7) & 0xFFu;
    c += (e >= 100u && e < 128u) ? 1 : 0;
  }
  atomicAdd(&cnt, c);
  __syncthreads();
  if (threadIdx.x == 0) *flag = (cnt < 256) ? 1 : 0;   // 1 => fp32 inputs/outputs
}

// ---------------- kernel 0: pos -> float4 {x,y,z,sq} ----------------
__global__ __launch_bounds__(256) void k_posf(const void* __restrict__ pos, float4* __restrict__ posf,
                                              const int* __restrict__ flag){
#pragma clang fp contract(off)
  int f32 = *flag;
  int p = blockIdx.x*256 + threadIdx.x;
  if (p >= NPTS) return;
  float x = ldin(pos, (long)p*3+0, f32);
  float y = ldin(pos, (long)p*3+1, f32);
  float z = ldin(pos, (long)p*3+2, f32);
  float px = x*x; float py = y*y; float pz = z*z;
  float sq = (px + py) + pz;   // match np.sum(pos*pos,-1) sequential order
  posf[p] = make_float4(x, y, z, sq);
}

// ---------------- kernel 1: exact 17-NN selection (one block per query) ----------------
// Per-wave 12-bit-prefix binary search (R3-proven pattern, deepened: exponent +
// 4 mantissa bits, shift 19) -> tight global threshold via atomicMin. Safety:
// {u < ut} is downward-closed, and the minimizing wave guarantees cnt >= 17,
// so the collected set provably contains the true top-17; exact rank follows.
// No LDS histograms (R6's 4.6e7 same-address atomic conflict cycles removed).
__global__ __launch_bounds__(256) void k_knn(const float4* __restrict__ posf, int* __restrict__ knn){
#pragma clang fp contract(off)
  __shared__ u64 scand[CAP];
  __shared__ int scnt;
  __shared__ uint sut;
  int qid = blockIdx.x;
  int b = qid >> 12;
  int tid = threadIdx.x;
  int lane = tid & 63;
  if (tid == 0){ scnt = 0; sut = 0xFFFFFFFFu; }
  __syncthreads();
  const float4 q = posf[qid];
  int jbase = b << 12;
  float d2[16]; uint ub[16];
  #pragma unroll
  for (int s = 0; s < 16; ++s){
    int j = s*256 + tid;
    float4 pj = posf[jbase + j];
    float ax = q.x*pj.x; float ay = q.y*pj.y; float az = q.z*pj.z;
    float dot = (ax + ay) + az;                 // match np einsum order
    float t  = q.w + pj.w;                      // sq_i + sq_j (one rounding)
    float v  = t - 2.0f*dot;                    // 2*dot exact, one rounding
    d2[s] = v;
    ub[s] = __float_as_uint(fmaxf(v, 0.0f));    // nonneg float: uint order == float order
  }
  // per-wave binary search: smallest granule g in [0,4096) with
  // count(ub < (g+1)<<19) >= 17 within this wave's 1024 values.
  // Init bracket valid: all ub <= 0x7F800000 < (4096<<19) = 2^31.
  int lo = 0, hi = 4095;
  while (lo < hi){
    int mid = (lo + hi) >> 1;
    uint T = (uint)(mid+1) << 19;
    int c = 0;
    #pragma unroll
    for (int s = 0; s < 16; ++s) c += (ub[s] < T) ? 1 : 0;
    #pragma unroll
    for (int off = 1; off < 64; off <<= 1) c += __shfl_xor(c, off, 64);
    if (c >= 17) hi = mid; else lo = mid + 1;
  }
  if (lane == 0) atomicMin(&sut, (uint)(lo+1) << 19);
  __syncthreads();
  uint ut = sut;
  // collect candidates below ut (cnt >= 17 guaranteed by minimizing wave)
  #pragma unroll
  for (int s = 0; s < 16; ++s){
    if (ub[s] < ut){
      int p = atomicAdd(&scnt, 1);
      if (p < CAP){
        uint w = __float_as_uint(d2[s]);
        uint sd = w ^ ((w & 0x80000000u) ? 0xFFFFFFFFu : 0x80000000u); // signed monotone map
        scand[p] = (((u64)sd) << 32) | (uint)(s*256 + tid);
      }
    }
  }
  __syncthreads();
  int cnt = scnt; if (cnt > CAP) cnt = CAP;
  // exact rank among candidates (unique keys -> ranks 0..cnt-1 all present)
  for (int base = 0; base < cnt; base += 256){
    int ci = base + tid;
    u64 mykey = (ci < cnt) ? scand[ci] : ~0ull;
    int r = 0;
    for (int i = 0; i < cnt; ++i){
      r += (scand[i] < mykey) ? 1 : 0;
    }
    if (ci < cnt && r >= 1 && r <= 16){
      knn[qid*16 + (r-1)] = (int)(mykey & 0xFFFFFFFFu);  // local j in [0,4096)
    }
  }
}

// ---------------- kernel W: weight prep ----------------
__global__ __launch_bounds__(256) void k_wprep(const void* __restrict__ Wf, const void* __restrict__ bfv,
                        const void* __restrict__ Wm1, const void* __restrict__ bm1,
                        const void* __restrict__ Wm2, const void* __restrict__ bm2,
                        const void* __restrict__ Wl, const void* __restrict__ bl,
                        ushort_t* __restrict__ WcatT, float* __restrict__ biasT,
                        ushort_t* __restrict__ WTA1, ushort_t* __restrict__ WTB2, ushort_t* __restrict__ WTC3,
                        const int* __restrict__ flag){
  int f32 = *flag;
  int id = blockIdx.x*256 + threadIdx.x;
  if (id < 40960){
    int n = id >> 7, k = id & 127;
    float v;
    if (n < 64)       v = ldin(Wf, (long)k*64 + n, f32) - ldin(Wf, (long)(256+k)*64 + n, f32);
    else if (n < 128) v = ldin(Wf, (long)(128+k)*64 + (n-64), f32) + ldin(Wf, (long)(256+k)*64 + (n-64), f32);
    else if (n < 192) v = ldin(Wm1, (long)(64+k)*64 + (n-128), f32);
    else if (n < 256) v = ldin(Wm2, (long)(128+k)*64 + (n-192), f32);
    else              v = ldin(Wl, (long)(192+k)*64 + (n-256), f32);
    WcatT[id] = f2bf(v);
  } else if (id < 41280){
    int n = id - 40960;
    float bv;
    if (n < 64)       bv = ldin(bfv, n, f32);
    else if (n < 128) bv = 0.0f;
    else if (n < 192) bv = ldin(bm1, n-128, f32);
    else if (n < 256) bv = ldin(bm2, n-192, f32);
    else              bv = ldin(bl, n-256, f32);
    biasT[n] = bv;
  } else if (id < 45376){      // WTA1 64x64
    int t = id - 41280; int n = t >> 6, k = t & 63;
    WTA1[t] = f2bf(ldin(Wm1, (long)k*64 + n, f32));
  } else if (id < 53568){      // WTB2 64x128
    int t = id - 45376; int n = t >> 7, k = t & 127;
    WTB2[t] = f2bf(ldin(Wm2, (long)k*64 + n, f32));
  } else if (id < 65856){      // WTC3 64x192
    int t = id - 53568; int n = t / 192, k = t % 192;
    WTC3[t] = f2bf(ldin(Wl, (long)k*64 + n, f32));
  }
}

// ---------------- kernel 2: P = X @ Wcat + bias  (bf16 out, rows 32768 x 320) ----------------
__global__ __launch_bounds__(256) void k_pgemm(const void* __restrict__ xv, const ushort_t* __restrict__ WcatT,
                                               const float* __restrict__ biasT, ushort_t* __restrict__ P,
                                               const int* __restrict__ flag){
  int f32 = *flag;
  int wave = threadIdx.x >> 6, lane = threadIdx.x & 63;
  int rowbase = blockIdx.x*64 + wave*16;
  int quad = lane >> 4, col = lane & 15;
  floatx4 acc[20];
  #pragma unroll
  for (int i = 0; i < 20; ++i) acc[i] = (floatx4){0.f,0.f,0.f,0.f};
  #pragma unroll
  for (int kk = 0; kk < 4; ++kk){
    int k = kk*32 + quad*8;
    short8 a;
    if (f32){
      const float* xf = (const float*)xv + (long)(rowbase + col)*128 + k;
      #pragma unroll
      for (int i = 0; i < 8; ++i) a[i] = (short)f2bf(xf[i]);
    } else {
      a = *(const short8*)((const ushort_t*)xv + (long)(rowbase + col)*128 + k);
    }
    #pragma unroll
    for (int nt = 0; nt < 20; ++nt){
      short8 bb = *(const short8*)(WcatT + (nt*16 + col)*128 + k);
      acc[nt] = __builtin_amdgcn_mfma_f32_16x16x32_bf16(a, bb, acc[nt], 0, 0, 0);
    }
  }
  #pragma unroll
  for (int nt = 0; nt < 20; ++nt){
    float bv = biasT[nt*16 + col];
    #pragma unroll
    for (int r = 0; r < 4; ++r){
      int m = quad*4 + r;
      P[(long)(rowbase + m)*320 + nt*16 + col] = f2bf(acc[nt][r] + bv);
    }
  }
}

// ---------------- kernel 3: per-edge chain + max over K (one wave per query) ----------------
__global__ __launch_bounds__(256) void k_edge(const void* __restrict__ x, const ushort_t* __restrict__ P,
                                              const int* __restrict__ knn,
                                              const ushort_t* __restrict__ WTA1, const ushort_t* __restrict__ WTB2,
                                              const ushort_t* __restrict__ WTC3, void* __restrict__ out,
                                              const int* __restrict__ flag){
  __shared__ __align__(16) ushort_t hb[4][3][16*72];   // per-wave h1,h2,h3 tiles, 72-elem padded rows
  int f32 = *flag;
  int wave = threadIdx.x >> 6, lane = threadIdx.x & 63;
  int qid = blockIdx.x*4 + wave;
  int b = qid >> 12;
  int quad = lane >> 4, col = lane & 15;
  ushort_t* h1p = hb[wave][0];
  ushort_t* h2p = hb[wave][1];
  ushort_t* h3p = hb[wave][2];
  const ushort_t* Prow = P + (long)qid*320;

  float u1v[4], u2v[4], u3v[4];
  #pragma unroll
  for (int nt = 0; nt < 4; ++nt){
    u1v[nt] = bf2f(Prow[128 + nt*16 + col]);
    u2v[nt] = bf2f(Prow[192 + nt*16 + col]);
    u3v[nt] = bf2f(Prow[256 + nt*16 + col]);
  }

  // h1 = relu(q_i + k_j): lane -> edge e=lane>>2, col-group cg=lane&3
  {
    int e = lane >> 2, cg = lane & 3;
    int nbr = knn[qid*16 + e] & (NP - 1);   // mask: any corrupt idx stays in-bounds
    const ushort_t* Pk = P + ((long)(b<<12) + nbr)*320 + 64 + cg*16;
    const ushort_t* Pq = Prow + cg*16;
    short8 k0 = *(const short8*)(Pk);
    short8 k1 = *(const short8*)(Pk + 8);
    short8 q0 = *(const short8*)(Pq);
    short8 q1 = *(const short8*)(Pq + 8);
    short8 h0, h1r;
    #pragma unroll
    for (int i = 0; i < 8; ++i){
      float v = fmaxf(bf2f((ushort_t)q0[i]) + bf2f((ushort_t)k0[i]), 0.0f);
      h0[i] = (short)f2bf(v);
      float w = fmaxf(bf2f((ushort_t)q1[i]) + bf2f((ushort_t)k1[i]), 0.0f);
      h1r[i] = (short)f2bf(w);
    }
    *(short8*)(h1p + e*72 + cg*16)     = h0;
    *(short8*)(h1p + e*72 + cg*16 + 8) = h1r;
  }
  __syncthreads();

  // layer 2: h2 = relu(h1 @ A1 + u1)
  floatx4 acc2[4];
  #pragma unroll
  for (int nt = 0; nt < 4; ++nt) acc2[nt] = (floatx4){0.f,0.f,0.f,0.f};
  #pragma unroll
  for (int kk = 0; kk < 2; ++kk){
    int k = kk*32 + quad*8;
    short8 a = *(const short8*)(h1p + col*72 + k);
    #pragma unroll
    for (int nt = 0; nt < 4; ++nt){
      short8 bb = *(const short8*)(WTA1 + (nt*16 + col)*64 + k);
      acc2[nt] = __builtin_amdgcn_mfma_f32_16x16x32_bf16(a, bb, acc2[nt], 0, 0, 0);
    }
  }
  #pragma unroll
  for (int nt = 0; nt < 4; ++nt){
    #pragma unroll
    for (int r = 0; r < 4; ++r){
      int m = quad*4 + r;
      h2p[m*72 + nt*16 + col] = f2bf(fmaxf(acc2[nt][r] + u1v[nt], 0.0f));
    }
  }
  __syncthreads();

  // layer 3: h3 = relu([h2|h1] @ B2 + u2)
  floatx4 acc3[4];
  #pragma unroll
  for (int nt = 0; nt < 4; ++nt) acc3[nt] = (floatx4){0.f,0.f,0.f,0.f};
  #pragma unroll
  for (int kk = 0; kk < 4; ++kk){
    int kg = kk*32 + quad*8;
    const ushort_t* src = (kk < 2) ? h2p : h1p;
    int kl = (kk < 2) ? kg : (kg - 64);
    short8 a = *(const short8*)(src + col*72 + kl);
    #pragma unroll
    for (int nt = 0; nt < 4; ++nt){
      short8 bb = *(const short8*)(WTB2 + (nt*16 + col)*128 + kg);
      acc3[nt] = __builtin_amdgcn_mfma_f32_16x16x32_bf16(a, bb, acc3[nt], 0, 0, 0);
    }
  }
  #pragma unroll
  for (int nt = 0; nt < 4; ++nt){
    #pragma unroll
    for (int r = 0; r < 4; ++r){
      int m = quad*4 + r;
      h3p[m*72 + nt*16 + col] = f2bf(fmaxf(acc3[nt][r] + u2v[nt], 0.0f));
    }
  }
  __syncthreads();

  // layer 4: o = [h3|h2|h1] @ C3 + u3  (no relu)
  floatx4 acc4[4];
  #pragma unroll
  for (int nt = 0; nt < 4; ++nt) acc4[nt] = (floatx4){0.f,0.f,0.f,0.f};
  #pragma unroll
  for (int kk = 0; kk < 6; ++kk){
    int kg = kk*32 + quad*8;
    const ushort_t* src = (kk < 2) ? h3p : ((kk < 4) ? h2p : h1p);
    int kl = (kk < 2) ? kg : ((kk < 4) ? (kg - 64) : (kg - 128));
    short8 a = *(const short8*)(src + col*72 + kl);
    #pragma unroll
    for (int nt = 0; nt < 4; ++nt){
      short8 bb = *(const short8*)(WTC3 + (nt*16 + col)*192 + kg);
      acc4[nt] = __builtin_amdgcn_mfma_f32_16x16x32_bf16(a, bb, acc4[nt], 0, 0, 0);
    }
  }

  // output: [max o | max h3 | max h2 | max h1 | x]
  long outb = (long)qid*384;
  #pragma unroll
  for (int nt = 0; nt < 4; ++nt){
    float m0 = fmaxf(fmaxf(acc4[nt][0], acc4[nt][1]), fmaxf(acc4[nt][2], acc4[nt][3])) + u3v[nt];
    m0 = fmaxf(m0, __shfl_xor(m0, 16, 64));
    m0 = fmaxf(m0, __shfl_xor(m0, 32, 64));
    if (lane < 16) stout(out, outb + nt*16 + lane, m0, f32);
  }
  {
    ushort_t mx3 = 0, mx2 = 0, mx1 = 0;
    #pragma unroll
    for (int m = 0; m < 16; ++m){
      ushort_t v3 = h3p[m*72 + lane]; if (v3 > mx3) mx3 = v3;
      ushort_t v2 = h2p[m*72 + lane]; if (v2 > mx2) mx2 = v2;
      ushort_t v1 = h1p[m*72 + lane]; if (v1 > mx1) mx1 = v1;
    }
    // post-relu bf16 >= 0: bit compare == float compare; bf2f/f2bf round-trip is identity
    stout(out, outb + 64  + lane, bf2f(mx3), f32);
    stout(out, outb + 128 + lane, bf2f(mx2), f32);
    stout(out, outb + 192 + lane, bf2f(mx1), f32);
    stout(out, outb + 256 + lane,      ldin(x, (long)qid*128 + lane, f32), f32);
    stout(out, outb + 256 + 64 + lane, ldin(x, (long)qid*128 + 64 + lane, f32), f32);
  }
}

extern "C" void kernel_launch(void* const* d_in, const int* in_sizes, int n_in,
                              void* d_out, int out_size, void* d_ws, size_t ws_size,
                              hipStream_t stream){
  const void* x   = d_in[0];
  const void* pos = d_in[1];
  const void* Wf  = d_in[2];
  const void* bfv = d_in[3];
  const void* Wm1 = d_in[4];
  const void* bm1 = d_in[5];
  const void* Wm2 = d_in[6];
  const void* bm2 = d_in[7];
  const void* Wl  = d_in[8];
  const void* bl  = d_in[9];
  char* ws = (char*)d_ws;
  float4*   posf  = (float4*)(ws + 0);                 // 524288 B
  int*      knn   = (int*)(ws + 524288);               // 2097152 B
  ushort_t* P     = (ushort_t*)(ws + 2621440);         // 20971520 B
  ushort_t* WcatT = (ushort_t*)(ws + 23592960);        // 81920 B
  float*    biasT = (float*)(ws + 23674880);           // 1280 B
  ushort_t* WTA1  = (ushort_t*)(ws + 23676160);        // 8192 B
  ushort_t* WTB2  = (ushort_t*)(ws + 23684352);        // 16384 B
  ushort_t* WTC3  = (ushort_t*)(ws + 23700736);        // 24576 B
  int*      flag  = (int*)(ws + 23725312);             // 4 B (total ~22.63 MB)

  k_detect<<<1,     256, 0, stream>>>((const uint*)Wf, flag);
  k_posf <<<128,   256, 0, stream>>>(pos, posf, flag);
  k_wprep<<<258,   256, 0, stream>>>(Wf, bfv, Wm1, bm1, Wm2, bm2, Wl, bl, WcatT, biasT, WTA1, WTB2, WTC3, flag);
  k_knn  <<<32768, 256, 0, stream>>>(posf, knn);
  k_pgemm<<<512,   256, 0, stream>>>(x, WcatT, biasT, P, flag);
  k_edge <<<8192,  256, 0, stream>>>(x, P, knn, WTA1, WTB2, WTC3, d_out, flag);
}

// Round 8
// 414.337 us; speedup vs baseline: 1.2430x; 1.2120x over previous
//
#include <hip/hip_runtime.h>
#include <hip/hip_bf16.h>

typedef unsigned int uint;
typedef unsigned short ushort_t;
typedef unsigned long long u64;
typedef __attribute__((ext_vector_type(8))) short short8;
typedef __attribute__((ext_vector_type(4))) float floatx4;

#define NB 8
#define NP 4096
#define ND 128
#define NK 16
#define NC 64
#define NPTS 32768   // NB*NP
#define CAP 1280     // candidate buffer; lane-min threshold keeps cnt ~20-60 typically

__device__ __forceinline__ float bf2f(ushort_t h){ return __uint_as_float(((uint)h)<<16); }
__device__ __forceinline__ ushort_t f2bf(float f){
  uint u = __float_as_uint(f);
  u = u + 0x7FFFu + ((u>>16)&1u);
  return (ushort_t)(u>>16);
}
// dtype-polymorphic input load (f32=1: fp32 array, f32=0: bf16 array)
__device__ __forceinline__ float ldin(const void* p, long i, int f32){
  return f32 ? ((const float*)p)[i] : bf2f(((const ushort_t*)p)[i]);
}
// dtype-polymorphic output store
__device__ __forceinline__ void stout(void* o, long i, float v, int f32){
  if (f32) ((float*)o)[i] = v; else ((ushort_t*)o)[i] = f2bf(v);
}

// ---------------- kernel D: detect input dtype ----------------
__global__ __launch_bounds__(256) void k_detect(const uint* __restrict__ w, int* __restrict__ flag){
  __shared__ int cnt;
  if (threadIdx.x == 0) cnt = 0;
  __syncthreads();
  int c = 0;
  for (int i = threadIdx.x; i < 512; i += 256){
    uint u = w[i];
    uint e = (u >> 7) & 0xFFu;
    c += (e >= 100u && e < 128u) ? 1 : 0;
  }
  atomicAdd(&cnt, c);
  __syncthreads();
  if (threadIdx.x == 0) *flag = (cnt < 256) ? 1 : 0;   // 1 => fp32 inputs/outputs
}

// ---------------- kernel 0: pos -> float4 {x,y,z,sq} ----------------
__global__ __launch_bounds__(256) void k_posf(const void* __restrict__ pos, float4* __restrict__ posf,
                                              const int* __restrict__ flag){
#pragma clang fp contract(off)
  int f32 = *flag;
  int p = blockIdx.x*256 + threadIdx.x;
  if (p >= NPTS) return;
  float x = ldin(pos, (long)p*3+0, f32);
  float y = ldin(pos, (long)p*3+1, f32);
  float z = ldin(pos, (long)p*3+2, f32);
  float px = x*x; float py = y*y; float pz = z*z;
  float sq = (px + py) + pz;   // match np.sum(pos*pos,-1) sequential order
  posf[p] = make_float4(x, y, z, sq);
}

// ---------------- kernel 1: exact 17-NN selection (one block per query) ----------------
// Threshold via lane-minima + ballot binary search (NO cross-lane shuffles, no
// LDS in the search — R3/R7's 72-deep ds_swizzle dependency chain removed).
// Validity: the 17th-smallest of a wave's 64 lane-minima T satisfies
// count(wave values <= T) >= 17 (17 distinct lanes each own >= 1 value <= T),
// and {u < ut} is downward-closed, so the collected set contains the true
// top-17; exact rank over candidates finishes the job. atomicMin over waves
// preserves the guarantee via the minimizing wave.
__global__ __launch_bounds__(256) void k_knn(const float4* __restrict__ posf, int* __restrict__ knn){
#pragma clang fp contract(off)
  __shared__ u64 scand[CAP];
  __shared__ int scnt;
  __shared__ uint sut;
  int qid = blockIdx.x;
  int b = qid >> 12;
  int tid = threadIdx.x;
  int lane = tid & 63;
  if (tid == 0){ scnt = 0; sut = 0xFFFFFFFFu; }
  __syncthreads();
  const float4 q = posf[qid];
  int jbase = b << 12;
  float d2[16]; uint ub[16];
  #pragma unroll
  for (int s = 0; s < 16; ++s){
    int j = s*256 + tid;
    float4 pj = posf[jbase + j];
    float ax = q.x*pj.x; float ay = q.y*pj.y; float az = q.z*pj.z;
    float dot = (ax + ay) + az;                 // match np einsum order
    float t  = q.w + pj.w;                      // sq_i + sq_j (one rounding)
    float v  = t - 2.0f*dot;                    // 2*dot exact, one rounding
    d2[s] = v;
    ub[s] = __float_as_uint(fmaxf(v, 0.0f));    // nonneg float: uint order == float order
  }
  // per-lane min of its 16 values (register-only)
  uint lm = ub[0];
  #pragma unroll
  for (int s = 1; s < 16; ++s) lm = (ub[s] < lm) ? ub[s] : lm;
  // per-wave binary search on 12-bit granules over the 64 lane-minima:
  // smallest g with popcount(lm < (g+1)<<19) >= 17. Scalar loop control +
  // ballot counting: ~1 VALU + ~4 SALU per iteration, no LDS, no shuffles.
  // Bracket valid: all lm <= 0x7F800000 < (4096<<19) = 2^31.
  int lo = 0, hi = 4095;
  while (lo < hi){
    int mid = (lo + hi) >> 1;
    uint T = (uint)(mid+1) << 19;
    u64 bal = __ballot(lm < T);
    if (__popcll(bal) >= 17) hi = mid; else lo = mid + 1;
  }
  if (lane == 0) atomicMin(&sut, (uint)(lo+1) << 19);
  __syncthreads();
  uint ut = sut;
  // collect candidates below ut (cnt >= 17 guaranteed by minimizing wave)
  #pragma unroll
  for (int s = 0; s < 16; ++s){
    if (ub[s] < ut){
      int p = atomicAdd(&scnt, 1);
      if (p < CAP){
        uint w = __float_as_uint(d2[s]);
        uint sd = w ^ ((w & 0x80000000u) ? 0xFFFFFFFFu : 0x80000000u); // signed monotone map
        scand[p] = (((u64)sd) << 32) | (uint)(s*256 + tid);
      }
    }
  }
  __syncthreads();
  int cnt = scnt; if (cnt > CAP) cnt = CAP;
  // exact rank among candidates (unique keys -> ranks 0..cnt-1 all present)
  for (int base = 0; base < cnt; base += 256){
    int ci = base + tid;
    u64 mykey = (ci < cnt) ? scand[ci] : ~0ull;
    int r = 0;
    for (int i = 0; i < cnt; ++i){
      r += (scand[i] < mykey) ? 1 : 0;
    }
    if (ci < cnt && r >= 1 && r <= 16){
      knn[qid*16 + (r-1)] = (int)(mykey & 0xFFFFFFFFu);  // local j in [0,4096)
    }
  }
}

// ---------------- kernel W: weight prep ----------------
__global__ __launch_bounds__(256) void k_wprep(const void* __restrict__ Wf, const void* __restrict__ bfv,
                        const void* __restrict__ Wm1, const void* __restrict__ bm1,
                        const void* __restrict__ Wm2, const void* __restrict__ bm2,
                        const void* __restrict__ Wl, const void* __restrict__ bl,
                        ushort_t* __restrict__ WcatT, float* __restrict__ biasT,
                        ushort_t* __restrict__ WTA1, ushort_t* __restrict__ WTB2, ushort_t* __restrict__ WTC3,
                        const int* __restrict__ flag){
  int f32 = *flag;
  int id = blockIdx.x*256 + threadIdx.x;
  if (id < 40960){
    int n = id >> 7, k = id & 127;
    float v;
    if (n < 64)       v = ldin(Wf, (long)k*64 + n, f32) - ldin(Wf, (long)(256+k)*64 + n, f32);
    else if (n < 128) v = ldin(Wf, (long)(128+k)*64 + (n-64), f32) + ldin(Wf, (long)(256+k)*64 + (n-64), f32);
    else if (n < 192) v = ldin(Wm1, (long)(64+k)*64 + (n-128), f32);
    else if (n < 256) v = ldin(Wm2, (long)(128+k)*64 + (n-192), f32);
    else              v = ldin(Wl, (long)(192+k)*64 + (n-256), f32);
    WcatT[id] = f2bf(v);
  } else if (id < 41280){
    int n = id - 40960;
    float bv;
    if (n < 64)       bv = ldin(bfv, n, f32);
    else if (n < 128) bv = 0.0f;
    else if (n < 192) bv = ldin(bm1, n-128, f32);
    else if (n < 256) bv = ldin(bm2, n-192, f32);
    else              bv = ldin(bl, n-256, f32);
    biasT[n] = bv;
  } else if (id < 45376){      // WTA1 64x64
    int t = id - 41280; int n = t >> 6, k = t & 63;
    WTA1[t] = f2bf(ldin(Wm1, (long)k*64 + n, f32));
  } else if (id < 53568){      // WTB2 64x128
    int t = id - 45376; int n = t >> 7, k = t & 127;
    WTB2[t] = f2bf(ldin(Wm2, (long)k*64 + n, f32));
  } else if (id < 65856){      // WTC3 64x192
    int t = id - 53568; int n = t / 192, k = t % 192;
    WTC3[t] = f2bf(ldin(Wl, (long)k*64 + n, f32));
  }
}

// ---------------- kernel 2: P = X @ Wcat + bias  (bf16 out, rows 32768 x 320) ----------------
__global__ __launch_bounds__(256) void k_pgemm(const void* __restrict__ xv, const ushort_t* __restrict__ WcatT,
                                               const float* __restrict__ biasT, ushort_t* __restrict__ P,
                                               const int* __restrict__ flag){
  int f32 = *flag;
  int wave = threadIdx.x >> 6, lane = threadIdx.x & 63;
  int rowbase = blockIdx.x*64 + wave*16;
  int quad = lane >> 4, col = lane & 15;
  floatx4 acc[20];
  #pragma unroll
  for (int i = 0; i < 20; ++i) acc[i] = (floatx4){0.f,0.f,0.f,0.f};
  #pragma unroll
  for (int kk = 0; kk < 4; ++kk){
    int k = kk*32 + quad*8;
    short8 a;
    if (f32){
      const float* xf = (const float*)xv + (long)(rowbase + col)*128 + k;
      #pragma unroll
      for (int i = 0; i < 8; ++i) a[i] = (short)f2bf(xf[i]);
    } else {
      a = *(const short8*)((const ushort_t*)xv + (long)(rowbase + col)*128 + k);
    }
    #pragma unroll
    for (int nt = 0; nt < 20; ++nt){
      short8 bb = *(const short8*)(WcatT + (nt*16 + col)*128 + k);
      acc[nt] = __builtin_amdgcn_mfma_f32_16x16x32_bf16(a, bb, acc[nt], 0, 0, 0);
    }
  }
  #pragma unroll
  for (int nt = 0; nt < 20; ++nt){
    float bv = biasT[nt*16 + col];
    #pragma unroll
    for (int r = 0; r < 4; ++r){
      int m = quad*4 + r;
      P[(long)(rowbase + m)*320 + nt*16 + col] = f2bf(acc[nt][r] + bv);
    }
  }
}

// ---------------- kernel 3: per-edge chain + max over K (one wave per query) ----------------
__global__ __launch_bounds__(256) void k_edge(const void* __restrict__ x, const ushort_t* __restrict__ P,
                                              const int* __restrict__ knn,
                                              const ushort_t* __restrict__ WTA1, const ushort_t* __restrict__ WTB2,
                                              const ushort_t* __restrict__ WTC3, void* __restrict__ out,
                                              const int* __restrict__ flag){
  __shared__ __align__(16) ushort_t hb[4][3][16*72];   // per-wave h1,h2,h3 tiles, 72-elem padded rows
  int f32 = *flag;
  int wave = threadIdx.x >> 6, lane = threadIdx.x & 63;
  int qid = blockIdx.x*4 + wave;
  int b = qid >> 12;
  int quad = lane >> 4, col = lane & 15;
  ushort_t* h1p = hb[wave][0];
  ushort_t* h2p = hb[wave][1];
  ushort_t* h3p = hb[wave][2];
  const ushort_t* Prow = P + (long)qid*320;

  float u1v[4], u2v[4], u3v[4];
  #pragma unroll
  for (int nt = 0; nt < 4; ++nt){
    u1v[nt] = bf2f(Prow[128 + nt*16 + col]);
    u2v[nt] = bf2f(Prow[192 + nt*16 + col]);
    u3v[nt] = bf2f(Prow[256 + nt*16 + col]);
  }

  // h1 = relu(q_i + k_j): lane -> edge e=lane>>2, col-group cg=lane&3
  {
    int e = lane >> 2, cg = lane & 3;
    int nbr = knn[qid*16 + e] & (NP - 1);   // mask: any corrupt idx stays in-bounds
    const ushort_t* Pk = P + ((long)(b<<12) + nbr)*320 + 64 + cg*16;
    const ushort_t* Pq = Prow + cg*16;
    short8 k0 = *(const short8*)(Pk);
    short8 k1 = *(const short8*)(Pk + 8);
    short8 q0 = *(const short8*)(Pq);
    short8 q1 = *(const short8*)(Pq + 8);
    short8 h0, h1r;
    #pragma unroll
    for (int i = 0; i < 8; ++i){
      float v = fmaxf(bf2f((ushort_t)q0[i]) + bf2f((ushort_t)k0[i]), 0.0f);
      h0[i] = (short)f2bf(v);
      float w = fmaxf(bf2f((ushort_t)q1[i]) + bf2f((ushort_t)k1[i]), 0.0f);
      h1r[i] = (short)f2bf(w);
    }
    *(short8*)(h1p + e*72 + cg*16)     = h0;
    *(short8*)(h1p + e*72 + cg*16 + 8) = h1r;
  }
  __syncthreads();

  // layer 2: h2 = relu(h1 @ A1 + u1)
  floatx4 acc2[4];
  #pragma unroll
  for (int nt = 0; nt < 4; ++nt) acc2[nt] = (floatx4){0.f,0.f,0.f,0.f};
  #pragma unroll
  for (int kk = 0; kk < 2; ++kk){
    int k = kk*32 + quad*8;
    short8 a = *(const short8*)(h1p + col*72 + k);
    #pragma unroll
    for (int nt = 0; nt < 4; ++nt){
      short8 bb = *(const short8*)(WTA1 + (nt*16 + col)*64 + k);
      acc2[nt] = __builtin_amdgcn_mfma_f32_16x16x32_bf16(a, bb, acc2[nt], 0, 0, 0);
    }
  }
  #pragma unroll
  for (int nt = 0; nt < 4; ++nt){
    #pragma unroll
    for (int r = 0; r < 4; ++r){
      int m = quad*4 + r;
      h2p[m*72 + nt*16 + col] = f2bf(fmaxf(acc2[nt][r] + u1v[nt], 0.0f));
    }
  }
  __syncthreads();

  // layer 3: h3 = relu([h2|h1] @ B2 + u2)
  floatx4 acc3[4];
  #pragma unroll
  for (int nt = 0; nt < 4; ++nt) acc3[nt] = (floatx4){0.f,0.f,0.f,0.f};
  #pragma unroll
  for (int kk = 0; kk < 4; ++kk){
    int kg = kk*32 + quad*8;
    const ushort_t* src = (kk < 2) ? h2p : h1p;
    int kl = (kk < 2) ? kg : (kg - 64);
    short8 a = *(const short8*)(src + col*72 + kl);
    #pragma unroll
    for (int nt = 0; nt < 4; ++nt){
      short8 bb = *(const short8*)(WTB2 + (nt*16 + col)*128 + kg);
      acc3[nt] = __builtin_amdgcn_mfma_f32_16x16x32_bf16(a, bb, acc3[nt], 0, 0, 0);
    }
  }
  #pragma unroll
  for (int nt = 0; nt < 4; ++nt){
    #pragma unroll
    for (int r = 0; r < 4; ++r){
      int m = quad*4 + r;
      h3p[m*72 + nt*16 + col] = f2bf(fmaxf(acc3[nt][r] + u2v[nt], 0.0f));
    }
  }
  __syncthreads();

  // layer 4: o = [h3|h2|h1] @ C3 + u3  (no relu)
  floatx4 acc4[4];
  #pragma unroll
  for (int nt = 0; nt < 4; ++nt) acc4[nt] = (floatx4){0.f,0.f,0.f,0.f};
  #pragma unroll
  for (int kk = 0; kk < 6; ++kk){
    int kg = kk*32 + quad*8;
    const ushort_t* src = (kk < 2) ? h3p : ((kk < 4) ? h2p : h1p);
    int kl = (kk < 2) ? kg : ((kk < 4) ? (kg - 64) : (kg - 128));
    short8 a = *(const short8*)(src + col*72 + kl);
    #pragma unroll
    for (int nt = 0; nt < 4; ++nt){
      short8 bb = *(const short8*)(WTC3 + (nt*16 + col)*192 + kg);
      acc4[nt] = __builtin_amdgcn_mfma_f32_16x16x32_bf16(a, bb, acc4[nt], 0, 0, 0);
    }
  }

  // output: [max o | max h3 | max h2 | max h1 | x]
  long outb = (long)qid*384;
  #pragma unroll
  for (int nt = 0; nt < 4; ++nt){
    float m0 = fmaxf(fmaxf(acc4[nt][0], acc4[nt][1]), fmaxf(acc4[nt][2], acc4[nt][3])) + u3v[nt];
    m0 = fmaxf(m0, __shfl_xor(m0, 16, 64));
    m0 = fmaxf(m0, __shfl_xor(m0, 32, 64));
    if (lane < 16) stout(out, outb + nt*16 + lane, m0, f32);
  }
  {
    ushort_t mx3 = 0, mx2 = 0, mx1 = 0;
    #pragma unroll
    for (int m = 0; m < 16; ++m){
      ushort_t v3 = h3p[m*72 + lane]; if (v3 > mx3) mx3 = v3;
      ushort_t v2 = h2p[m*72 + lane]; if (v2 > mx2) mx2 = v2;
      ushort_t v1 = h1p[m*72 + lane]; if (v1 > mx1) mx1 = v1;
    }
    // post-relu bf16 >= 0: bit compare == float compare; bf2f/f2bf round-trip is identity
    stout(out, outb + 64  + lane, bf2f(mx3), f32);
    stout(out, outb + 128 + lane, bf2f(mx2), f32);
    stout(out, outb + 192 + lane, bf2f(mx1), f32);
    stout(out, outb + 256 + lane,      ldin(x, (long)qid*128 + lane, f32), f32);
    stout(out, outb + 256 + 64 + lane, ldin(x, (long)qid*128 + 64 + lane, f32), f32);
  }
}

extern "C" void kernel_launch(void* const* d_in, const int* in_sizes, int n_in,
                              void* d_out, int out_size, void* d_ws, size_t ws_size,
                              hipStream_t stream){
  const void* x   = d_in[0];
  const void* pos = d_in[1];
  const void* Wf  = d_in[2];
  const void* bfv = d_in[3];
  const void* Wm1 = d_in[4];
  const void* bm1 = d_in[5];
  const void* Wm2 = d_in[6];
  const void* bm2 = d_in[7];
  const void* Wl  = d_in[8];
  const void* bl  = d_in[9];
  char* ws = (char*)d_ws;
  float4*   posf  = (float4*)(ws + 0);                 // 524288 B
  int*      knn   = (int*)(ws + 524288);               // 2097152 B
  ushort_t* P     = (ushort_t*)(ws + 2621440);         // 20971520 B
  ushort_t* WcatT = (ushort_t*)(ws + 23592960);        // 81920 B
  float*    biasT = (float*)(ws + 23674880);           // 1280 B
  ushort_t* WTA1  = (ushort_t*)(ws + 23676160);        // 8192 B
  ushort_t* WTB2  = (ushort_t*)(ws + 23684352);        // 16384 B
  ushort_t* WTC3  = (ushort_t*)(ws + 23700736);        // 24576 B
  int*      flag  = (int*)(ws + 23725312);             // 4 B (total ~22.63 MB)

  k_detect<<<1,     256, 0, stream>>>((const uint*)Wf, flag);
  k_posf <<<128,   256, 0, stream>>>(pos, posf, flag);
  k_wprep<<<258,   256, 0, stream>>>(Wf, bfv, Wm1, bm1, Wm2, bm2, Wl, bl, WcatT, biasT, WTA1, WTB2, WTC3, flag);
  k_knn  <<<32768, 256, 0, stream>>>(posf, knn);
  k_pgemm<<<512,   256, 0, stream>>>(x, WcatT, biasT, P, flag);
  k_edge <<<8192,  256, 0, stream>>>(x, P, knn, WTA1, WTB2, WTC3, d_out, flag);
}